// Round 4
// baseline (321.002 us; speedup 1.0000x reference)
//
#include <hip/hip_runtime.h>
#include <hip/hip_bf16.h>

#define B_N 16
#define L_N 9216
#define LT64 144    // L_N / 64

typedef __attribute__((ext_vector_type(8))) short short8;
typedef __attribute__((ext_vector_type(4))) float floatx4;

__device__ __forceinline__ float bfu(unsigned short u) {
  return __uint_as_float(((unsigned int)u) << 16);
}
__device__ __forceinline__ unsigned short fbf(float f) {
  __hip_bfloat16 h = __float2bfloat16(f);
  return *(unsigned short*)&h;
}

// ---------------------------------------------------------------------------
// K1: x (b,c=128,l) fp32 -> xt (b,l,c=128) bf16 transpose; blocks 0..127 also
// convert w1/w2 to bf16 (fused k_prep).
// ---------------------------------------------------------------------------
__global__ __launch_bounds__(256) void k_xt(const float* __restrict__ x,
                                            const float* __restrict__ w1,
                                            const float* __restrict__ w2,
                                            __hip_bfloat16* __restrict__ xt,
                                            __hip_bfloat16* __restrict__ w1bt,
                                            __hip_bfloat16* __restrict__ w2bt) {
  __shared__ float xs[128][65];
  int blk = blockIdx.x, b = blk / LT64, lt = blk % LT64, l0 = lt * 64;
  int t = threadIdx.x;
  if (blk < 128) {
    int i = blk * 256 + t;
    w1bt[i] = __float2bfloat16(w1[i]);
    if (i < 128 * 128) w2bt[i] = __float2bfloat16(w2[i]);
  }
  const float* xb = x + (size_t)b * 128 * L_N;
#pragma unroll
  for (int i = 0; i < 8; ++i) {
    int idx = t + i * 256;
    int c = idx >> 4, f4 = idx & 15;
    float4 v = *(const float4*)(xb + (size_t)c * L_N + l0 + f4 * 4);
    xs[c][f4 * 4 + 0] = v.x; xs[c][f4 * 4 + 1] = v.y;
    xs[c][f4 * 4 + 2] = v.z; xs[c][f4 * 4 + 3] = v.w;
  }
  __syncthreads();
  __hip_bfloat16* xtb = xt + ((size_t)b * L_N + l0) * 128;
#pragma unroll
  for (int i = 0; i < 16; ++i) {
    int idx = t + i * 256;
    int cp = idx & 63, l = idx >> 6;
    __hip_bfloat162 u;
    u.x = __float2bfloat16(xs[2 * cp][l]);
    u.y = __float2bfloat16(xs[2 * cp + 1][l]);
    *(__hip_bfloat162*)(xtb + (size_t)l * 128 + 2 * cp) = u;
  }
}

// ---------------------------------------------------------------------------
// K2: in_proj MFMA (M=256e x N=64l x K=128c) + depthwise conv(k=4) + SiLU +
// x_proj, all fused.  B-tile staged with a 16-row l-halo so boundary columns
// come from LDS.  cvs (bf16) aliases the dead B-tile -> 33 KB LDS total.
// ---------------------------------------------------------------------------
__global__ __launch_bounds__(256) void k_inproj_conv(
    const __hip_bfloat16* __restrict__ xt, const __hip_bfloat16* __restrict__ w1bt,
    const float* __restrict__ cw, const float* __restrict__ cb,
    const float* __restrict__ xpw,
    __hip_bfloat16* __restrict__ xinb, __hip_bfloat16* __restrict__ zb,
    __hip_bfloat16* __restrict__ xdblT) {
  __shared__ __align__(16) char smem[33792];
  __hip_bfloat16* xs = (__hip_bfloat16*)smem;      // [80][128] swizzled (20480 B)
  unsigned short* cvs = (unsigned short*)smem;     // [128][84] bf16 (21504 B, aliases xs)
  float* red = (float*)(smem + 21504);             // [4][12][64] (12288 B)
  int blk = blockIdx.x, b = blk / LT64, lt = blk % LT64, l0 = lt * 64;
  int t = threadIdx.x;
  // stage B-tile rows l0-16 .. l0+63 (zero-fill halo at lt==0)
  const __hip_bfloat16* src = xt + ((size_t)b * L_N + l0 - 16) * 128;
#pragma unroll
  for (int i = 0; i < 5; ++i) {
    int idx = t + i * 256;              // 1280 16B chunks (80 rows x 16)
    int row = idx >> 4, ch = idx & 15;
    uint4 v = make_uint4(0, 0, 0, 0);
    if (!(lt == 0 && row < 16)) v = *(const uint4*)(src + idx * 8);
    *(uint4*)&xs[row * 128 + ((ch ^ (row & 7)) * 8)] = v;
  }
  int lane = t & 63, wv = t >> 6;
  int col = lane & 15, quad = lane >> 4;
  int e0 = wv * 64;
  short8 afr[4][4];
  const __hip_bfloat16* wb = w1bt + (size_t)(e0 + col) * 128 + quad * 8;
#pragma unroll
  for (int mi = 0; mi < 4; ++mi)
#pragma unroll
    for (int ks = 0; ks < 4; ++ks)
      afr[mi][ks] = *(const short8*)(wb + mi * 16 * 128 + ks * 32);
  floatx4 vzero = {0.f, 0.f, 0.f, 0.f};
  floatx4 acc[4][4];
#pragma unroll
  for (int mi = 0; mi < 4; ++mi)
#pragma unroll
    for (int ni = 0; ni < 4; ++ni) acc[mi][ni] = vzero;
  __syncthreads();                               // B1
#pragma unroll
  for (int ks = 0; ks < 4; ++ks) {
    short8 bfr[4];
#pragma unroll
    for (int ni = 0; ni < 4; ++ni) {
      int row = 16 + ni * 16 + col;
      bfr[ni] = *(const short8*)&xs[row * 128 + (((ks * 4 + quad) ^ (row & 7)) * 8)];
    }
#pragma unroll
    for (int mi = 0; mi < 4; ++mi)
#pragma unroll
      for (int ni = 0; ni < 4; ++ni)
        acc[mi][ni] = __builtin_amdgcn_mfma_f32_16x16x32_bf16(afr[mi][ks], bfr[ni], acc[mi][ni], 0, 0, 0);
  }
  // boundary xinpre (l0-3..l0-1) for d = t < 128: x from LDS halo, w from L2
  float s0 = 0.f, s1 = 0.f, s2 = 0.f;
  if (t < 128) {
    const __hip_bfloat16* wr = w1bt + (size_t)t * 128;
#pragma unroll
    for (int c = 0; c < 16; ++c) {
      short8 wc = *(const short8*)(wr + c * 8);
      short8 xa = *(const short8*)&xs[13 * 128 + ((c ^ 5) * 8)];
      short8 xb2 = *(const short8*)&xs[14 * 128 + ((c ^ 6) * 8)];
      short8 xc = *(const short8*)&xs[15 * 128 + ((c ^ 7) * 8)];
#pragma unroll
      for (int e = 0; e < 8; ++e) {
        float wf = bfu((unsigned short)wc[e]);
        s0 += wf * bfu((unsigned short)xa[e]);
        s1 += wf * bfu((unsigned short)xb2[e]);
        s2 += wf * bfu((unsigned short)xc[e]);
      }
    }
  }
  __syncthreads();                               // B2: all xs reads done
  if (t < 128) {
    cvs[t * 84 + 0] = fbf(s0); cvs[t * 84 + 1] = fbf(s1); cvs[t * 84 + 2] = fbf(s2);
  }
  if (wv < 2) {
#pragma unroll
    for (int mi = 0; mi < 4; ++mi)
#pragma unroll
      for (int r = 0; r < 4; ++r) {
        int d = e0 + mi * 16 + quad * 4 + r;
#pragma unroll
        for (int ni = 0; ni < 4; ++ni)
          cvs[d * 84 + 3 + ni * 16 + col] = fbf(acc[mi][ni][r]);
      }
  } else {
    unsigned short* zbase = (unsigned short*)zb + ((size_t)b * 128 + (e0 - 128)) * L_N + l0;
#pragma unroll
    for (int mi = 0; mi < 4; ++mi)
#pragma unroll
      for (int r = 0; r < 4; ++r) {
        int dr = mi * 16 + quad * 4 + r;
#pragma unroll
        for (int ni = 0; ni < 4; ++ni)
          zbase[(size_t)dr * L_N + ni * 16 + col] = fbf(acc[mi][ni][r]);
      }
  }
  __syncthreads();                               // B3: cvs ready
  // conv + SiLU + x_proj; lane handles l-pair (i2, i2+1), d-halfstrip dh
  int i2 = 2 * (lane & 31), dh = lane >> 5;
  const unsigned int* cvw = (const unsigned int*)cvs;
  float part[12][2];
#pragma unroll
  for (int m = 0; m < 12; ++m) { part[m][0] = 0.f; part[m][1] = 0.f; }
  for (int dd = 0; dd < 16; ++dd) {
    int d = wv * 32 + dh * 16 + dd;
    unsigned int u0 = cvw[d * 42 + (i2 >> 1)];
    unsigned int u1 = cvw[d * 42 + (i2 >> 1) + 1];
    unsigned int u2 = cvw[d * 42 + (i2 >> 1) + 2];
    float x0 = bfu((unsigned short)u0), x1 = bfu((unsigned short)(u0 >> 16));
    float x2 = bfu((unsigned short)u1), x3 = bfu((unsigned short)(u1 >> 16));
    float x4 = bfu((unsigned short)u2);
    float c0 = cw[d * 4 + 0], c1 = cw[d * 4 + 1], c2 = cw[d * 4 + 2], c3 = cw[d * 4 + 3];
    float bb = cb[d];
    float va = bb + c0 * x0 + c1 * x1 + c2 * x2 + c3 * x3;
    float vb2 = bb + c0 * x1 + c1 * x2 + c2 * x3 + c3 * x4;
    va = va / (1.f + __expf(-va));
    vb2 = vb2 / (1.f + __expf(-vb2));
    unsigned int pu = (unsigned int)fbf(va) | ((unsigned int)fbf(vb2) << 16);
    *(unsigned int*)((unsigned short*)xinb + ((size_t)b * 128 + d) * L_N + l0 + i2) = pu;
#pragma unroll
    for (int m = 0; m < 12; ++m) {
      float wm = xpw[m * 128 + d];
      part[m][0] += wm * va; part[m][1] += wm * vb2;
    }
  }
#pragma unroll
  for (int m = 0; m < 12; ++m) {
    float v0 = part[m][0] + __shfl_xor(part[m][0], 32, 64);
    float v1 = part[m][1] + __shfl_xor(part[m][1], 32, 64);
    red[wv * 768 + m * 64 + i2 + dh] = dh ? v1 : v0;
  }
  __syncthreads();                               // B4
  for (int idx = t; idx < 768; idx += 256) {
    int m = idx >> 6, l = idx & 63;
    float s = red[m * 64 + l] + red[768 + m * 64 + l] + red[1536 + m * 64 + l] + red[2304 + m * 64 + l];
    ((unsigned short*)xdblT)[((size_t)b * 12 + m) * L_N + l0 + l] = fbf(s);
  }
}

// ---------------------------------------------------------------------------
// K3: dt_proj + softplus + scan (D_STATE=2) + y + z-gate.
// ONE WAVE per (b,d): no LDS, no barriers.  36 tiles of 256 l; 4 elems/lane
// serial + wave KS on aggregates; carry broadcast via shfl(63).
// Double-buffered prefetch of the 14 bf16 input streams.
// ---------------------------------------------------------------------------
__global__ __launch_bounds__(256) void k_scan(
    const __hip_bfloat16* __restrict__ xdblT, const float* __restrict__ dtw,
    const float* __restrict__ dtb, const float* __restrict__ alog,
    const float* __restrict__ dpar,
    const __hip_bfloat16* __restrict__ xinb, const __hip_bfloat16* __restrict__ zb,
    __hip_bfloat16* __restrict__ yb) {
  int t = threadIdx.x, lane = t & 63, wv = t >> 6;
  int p = blockIdx.x * 4 + wv;
  int b = p >> 7, d = p & 127;
  float A0 = -__expf(alog[2 * d]), A1 = -__expf(alog[2 * d + 1]);
  float Dv = dpar[d], dtbv = dtb[d];
  float w[8];
#pragma unroll
  for (int i = 0; i < 8; ++i) w[i] = dtw[d * 8 + i];
  const unsigned short* xdT = (const unsigned short*)xdblT + (size_t)b * 12 * L_N;
  const unsigned short* xi = (const unsigned short*)xinb + ((size_t)b * 128 + d) * L_N;
  const unsigned short* zr = (const unsigned short*)zb + ((size_t)b * 128 + d) * L_N;
  unsigned short* yo = (unsigned short*)yb + ((size_t)b * 128 + d) * L_N;
  float c0 = 0.f, c1 = 0.f;
  ushort4 q[2][12], xu[2], zu[2];
  {
    int lb = lane * 4;
#pragma unroll
    for (int m = 0; m < 12; ++m) q[0][m] = *(const ushort4*)(xdT + (size_t)m * L_N + lb);
    xu[0] = *(const ushort4*)(xi + lb);
    zu[0] = *(const ushort4*)(zr + lb);
  }
#pragma unroll 2
  for (int it = 0; it < 36; ++it) {
    int cur = it & 1, nxt = cur ^ 1;
    if (it < 35) {
      int lb = (it + 1) * 256 + lane * 4;
#pragma unroll
      for (int m = 0; m < 12; ++m) q[nxt][m] = *(const ushort4*)(xdT + (size_t)m * L_N + lb);
      xu[nxt] = *(const ushort4*)(xi + lb);
      zu[nxt] = *(const ushort4*)(zr + lb);
    }
    const unsigned short* qq = (const unsigned short*)&q[cur][0];  // 12 ushort4 contiguous
    float dtp[4];
#pragma unroll
    for (int j = 0; j < 4; ++j) dtp[j] = dtbv;
#pragma unroll
    for (int m = 0; m < 8; ++m)
#pragma unroll
      for (int j = 0; j < 4; ++j) dtp[j] += w[m] * bfu(qq[m * 4 + j]);
    const unsigned short* xup = (const unsigned short*)&xu[cur];
    const unsigned short* zup = (const unsigned short*)&zu[cur];
    float A0p[4], X0p[4], A1p[4], X1p[4], xv[4];
#pragma unroll
    for (int j = 0; j < 4; ++j) {
      float dt = (dtp[j] > 15.f) ? dtp[j] : __logf(1.f + __expf(dtp[j]));
      float a0 = __expf(dt * A0), a1 = __expf(dt * A1);
      xv[j] = bfu(xup[j]);
      float dtx = dt * xv[j];
      float x0 = dtx * bfu(qq[8 * 4 + j]);
      float x1 = dtx * bfu(qq[9 * 4 + j]);
      if (j == 0) { A0p[0] = a0; X0p[0] = x0; A1p[0] = a1; X1p[0] = x1; }
      else {
        A0p[j] = a0 * A0p[j - 1]; X0p[j] = a0 * X0p[j - 1] + x0;
        A1p[j] = a1 * A1p[j - 1]; X1p[j] = a1 * X1p[j - 1] + x1;
      }
    }
    float wA0 = A0p[3], wX0 = X0p[3], wA1 = A1p[3], wX1 = X1p[3];
#pragma unroll
    for (int off = 1; off < 64; off <<= 1) {
      float pA0 = __shfl_up(wA0, off, 64), pX0 = __shfl_up(wX0, off, 64);
      float pA1 = __shfl_up(wA1, off, 64), pX1 = __shfl_up(wX1, off, 64);
      if (lane >= off) {
        wX0 += wA0 * pX0; wA0 *= pA0;
        wX1 += wA1 * pX1; wA1 *= pA1;
      }
    }
    // exclusive per-lane entry state
    float eA0 = __shfl_up(wA0, 1, 64), eX0 = __shfl_up(wX0, 1, 64);
    float eA1 = __shfl_up(wA1, 1, 64), eX1 = __shfl_up(wX1, 1, 64);
    if (lane == 0) { eA0 = 1.f; eX0 = 0.f; eA1 = 1.f; eX1 = 0.f; }
    float h0 = eA0 * c0 + eX0;
    float h1 = eA1 * c1 + eX1;
    // new carry (wave-uniform broadcast of lane 63 totals)
    float tA0 = __shfl(wA0, 63, 64), tX0 = __shfl(wX0, 63, 64);
    float tA1 = __shfl(wA1, 63, 64), tX1 = __shfl(wX1, 63, 64);
    c0 = tA0 * c0 + tX0;
    c1 = tA1 * c1 + tX1;
    ushort4 yu;
    unsigned short* yp = (unsigned short*)&yu;
#pragma unroll
    for (int j = 0; j < 4; ++j) {
      float hh0 = A0p[j] * h0 + X0p[j];
      float hh1 = A1p[j] * h1 + X1p[j];
      float y = hh0 * bfu(qq[10 * 4 + j]) + hh1 * bfu(qq[11 * 4 + j]) + Dv * xv[j];
      float zvj = bfu(zup[j]);
      y *= zvj / (1.f + __expf(-zvj));
      yp[j] = fbf(y);
    }
    *(ushort4*)(yo + it * 256 + lane * 4) = yu;
  }
}

// ---------------------------------------------------------------------------
// K4: out_proj MFMA with SWAPPED roles (A=y: D row=l, col=o) + LayerNorm +
// NCHW write.  Each lane holds 4 consecutive l's -> float4 output stores.
// ---------------------------------------------------------------------------
__global__ __launch_bounds__(256) void k_outln(
    const __hip_bfloat16* __restrict__ yb, const __hip_bfloat16* __restrict__ w2bt,
    const float* __restrict__ gam, const float* __restrict__ bet,
    float* __restrict__ out) {
  __shared__ unsigned short st[128][68];
  __shared__ __hip_bfloat16 yts[64 * 128];
  __shared__ float red_s[4][64], red_q[4][64];
  __shared__ float mrs[64][2];
  int blk = blockIdx.x, b = blk / LT64, lt = blk % LT64, l0 = lt * 64;
  int t = threadIdx.x;
  const unsigned short* ybb = (const unsigned short*)yb + (size_t)b * 128 * L_N + l0;
#pragma unroll
  for (int i = 0; i < 8; ++i) {
    int idx = t + i * 256;
    int dd = idx >> 4, l4 = (idx & 15) * 4;
    *(ushort4*)&st[dd][l4] = *(const ushort4*)(ybb + (size_t)dd * L_N + l4);
  }
  __syncthreads();
#pragma unroll
  for (int p = 0; p < 4; ++p) {
    int gi = t + p * 256;
    int l = gi & 63, ch = gi >> 6;
    short8 c;
#pragma unroll
    for (int j = 0; j < 8; ++j) c[j] = (short)st[ch * 8 + j][l];
    *(short8*)&yts[l * 128 + ((ch ^ (l & 7)) * 8)] = c;
  }
  int lane = t & 63, wv = t >> 6;
  int col = lane & 15, quad = lane >> 4;
  short8 bfrw[2][4];
#pragma unroll
  for (int ni = 0; ni < 2; ++ni)
#pragma unroll
    for (int ks = 0; ks < 4; ++ks) {
      int o = wv * 32 + ni * 16 + col;
      bfrw[ni][ks] = *(const short8*)(w2bt + (size_t)o * 128 + ks * 32 + quad * 8);
    }
  floatx4 vzero = {0.f, 0.f, 0.f, 0.f};
  floatx4 acc[4][2];
#pragma unroll
  for (int mi = 0; mi < 4; ++mi)
#pragma unroll
    for (int ni = 0; ni < 2; ++ni) acc[mi][ni] = vzero;
  __syncthreads();
#pragma unroll
  for (int ks = 0; ks < 4; ++ks) {
    short8 afr[4];
#pragma unroll
    for (int mi = 0; mi < 4; ++mi) {
      int row = mi * 16 + col;
      afr[mi] = *(const short8*)&yts[row * 128 + (((ks * 4 + quad) ^ (row & 7)) * 8)];
    }
#pragma unroll
    for (int mi = 0; mi < 4; ++mi)
#pragma unroll
      for (int ni = 0; ni < 2; ++ni)
        acc[mi][ni] = __builtin_amdgcn_mfma_f32_16x16x32_bf16(afr[mi], bfrw[ni][ks], acc[mi][ni], 0, 0, 0);
  }
  // LN: reduce over o.  per (mi,r): in-lane over ni, shfl_xor over 16 cols.
#pragma unroll
  for (int mi = 0; mi < 4; ++mi)
#pragma unroll
    for (int r = 0; r < 4; ++r) {
      float v0 = acc[mi][0][r], v1 = acc[mi][1][r];
      float ss = v0 + v1, qq = v0 * v0 + v1 * v1;
      ss += __shfl_xor(ss, 1, 64); qq += __shfl_xor(qq, 1, 64);
      ss += __shfl_xor(ss, 2, 64); qq += __shfl_xor(qq, 2, 64);
      ss += __shfl_xor(ss, 4, 64); qq += __shfl_xor(qq, 4, 64);
      ss += __shfl_xor(ss, 8, 64); qq += __shfl_xor(qq, 8, 64);
      if (col == 0) {
        int l = mi * 16 + quad * 4 + r;
        red_s[wv][l] = ss; red_q[wv][l] = qq;
      }
    }
  __syncthreads();
  if (t < 64) {
    float ts = red_s[0][t] + red_s[1][t] + red_s[2][t] + red_s[3][t];
    float tq = red_q[0][t] + red_q[1][t] + red_q[2][t] + red_q[3][t];
    float m = ts * (1.f / 128.f);
    float var = tq * (1.f / 128.f) - m * m;
    mrs[t][0] = m;
    mrs[t][1] = rsqrtf(var + 1e-5f);
  }
  __syncthreads();
  float* ob = out + (size_t)b * 128 * L_N + l0;
#pragma unroll
  for (int mi = 0; mi < 4; ++mi) {
    float mu_[4], rs_[4];
#pragma unroll
    for (int r = 0; r < 4; ++r) {
      int l = mi * 16 + quad * 4 + r;
      float2 mr = *(const float2*)&mrs[l][0];
      mu_[r] = mr.x; rs_[r] = mr.y;
    }
#pragma unroll
    for (int ni = 0; ni < 2; ++ni) {
      int o = wv * 32 + ni * 16 + col;
      float g = gam[o], be = bet[o];
      float4 vv;
      vv.x = (acc[mi][ni][0] - mu_[0]) * rs_[0] * g + be;
      vv.y = (acc[mi][ni][1] - mu_[1]) * rs_[1] * g + be;
      vv.z = (acc[mi][ni][2] - mu_[2]) * rs_[2] * g + be;
      vv.w = (acc[mi][ni][3] - mu_[3]) * rs_[3] * g + be;
      *(float4*)(ob + (size_t)o * L_N + mi * 16 + quad * 4) = vv;
    }
  }
}

// ---------------------------------------------------------------------------
extern "C" void kernel_launch(void* const* d_in, const int* in_sizes, int n_in,
                              void* d_out, int out_size, void* d_ws, size_t ws_size,
                              hipStream_t stream) {
  const float* x    = (const float*)d_in[0];
  const float* w1   = (const float*)d_in[1];
  const float* cw   = (const float*)d_in[2];
  const float* cb   = (const float*)d_in[3];
  const float* xpw  = (const float*)d_in[4];
  const float* dtw  = (const float*)d_in[5];
  const float* dtb  = (const float*)d_in[6];
  const float* alog = (const float*)d_in[7];
  const float* dpar = (const float*)d_in[8];
  const float* w2   = (const float*)d_in[9];
  const float* gam  = (const float*)d_in[10];
  const float* bet  = (const float*)d_in[11];
  float* out = (float*)d_out;

  const size_t NBL = (size_t)B_N * 128 * L_N;      // 18,874,368
  __hip_bfloat16* xt    = (__hip_bfloat16*)d_ws;   // (B,L,128)
  __hip_bfloat16* xinb  = xt + NBL;                // (B,D,L)
  __hip_bfloat16* zbuf  = xinb + NBL;              // (B,D,L)
  __hip_bfloat16* ybuf  = zbuf + NBL;              // (B,D,L)
  __hip_bfloat16* xdblT = ybuf + NBL;              // (B,12,L)
  __hip_bfloat16* w1bt  = xdblT + (size_t)B_N * 12 * L_N;
  __hip_bfloat16* w2bt  = w1bt + 256 * 128;

  k_xt<<<B_N * LT64, 256, 0, stream>>>(x, w1, w2, xt, w1bt, w2bt);
  k_inproj_conv<<<B_N * LT64, 256, 0, stream>>>(xt, w1bt, cw, cb, xpw, xinb, zbuf, xdblT);
  k_scan<<<512, 256, 0, stream>>>(xdblT, dtw, dtb, alog, dpar, xinb, zbuf, ybuf);
  k_outln<<<B_N * LT64, 256, 0, stream>>>(ybuf, w2bt, gam, bet, out);
}